// Round 2
// baseline (68.622 us; speedup 1.0000x reference)
//
#include <hip/hip_runtime.h>

// state[2, 4096, 512] f32; out[n,i,b] = in[n, q(i), b] where q composes the 4
// CNOT permutations (last gate applied to the output index first).
// Pure row-permutation copy: each middle-index row is a contiguous 2 KiB blob.
//   p4=(11,7): if bit0 set flip bit4
//   p3=(5,2):  if bit6 set flip bit9
//   p2=(2,3):  if bit9 set flip bit8   (sees p3's update)
//   p1=(0,1):  if bit11 set flip bit10

typedef float f32x4 __attribute__((ext_vector_type(4)));

__device__ __forceinline__ int cnot_perm(int i) {
    int j = i;
    j ^= (j & 1) << 4;
    j ^= ((j >> 6) & 1) << 9;
    j ^= ((j >> 9) & 1) << 8;
    j ^= ((j >> 11) & 1) << 10;
    return j;
}

// 4 float4 per thread: thread t handles float4 indices {t + h*Q, h=0..3}.
// All 4 loads issued before any store (4 outstanding dwordx4 per thread),
// nontemporal on both sides (zero reuse; L3 is thrashed by harness poison
// fill anyway). 1024 blocks x 256 threads covers all 1,048,576 float4s.
__global__ void __launch_bounds__(256)
CNOT_layer_16140487098686_kernel(const f32x4* __restrict__ in,
                                 f32x4* __restrict__ out) {
    constexpr int TOTAL = 2 * 4096 * 128;   // 1048576 float4
    constexpr int Q = TOTAL / 4;            // 262144 float4 per quarter
    const int tid = blockIdx.x * blockDim.x + threadIdx.x;

    f32x4 v[4];
    #pragma unroll
    for (int h = 0; h < 4; ++h) {
        const int t   = tid + h * Q;
        const int off = t & 127;       // float4 index within 512-float batch row
        const int row = t >> 7;        // 0 .. 8191 (n*4096 + i)
        const int n   = row >> 12;
        const int i   = row & 4095;
        const int j   = cnot_perm(i);
        v[h] = __builtin_nontemporal_load(&in[(((n << 12) | j) << 7) | off]);
    }
    #pragma unroll
    for (int h = 0; h < 4; ++h) {
        __builtin_nontemporal_store(v[h], &out[tid + h * Q]);
    }
}

extern "C" void kernel_launch(void* const* d_in, const int* in_sizes, int n_in,
                              void* d_out, int out_size, void* d_ws, size_t ws_size,
                              hipStream_t stream) {
    const f32x4* in = (const f32x4*)d_in[0];
    f32x4* out = (f32x4*)d_out;
    constexpr int TOTAL = 2 * 4096 * 128;   // float4 count
    constexpr int threads_total = TOTAL / 4;
    CNOT_layer_16140487098686_kernel<<<threads_total / 256, 256, 0, stream>>>(in, out);
}